// Round 9
// baseline (526.299 us; speedup 1.0000x reference)
//
#include <hip/hip_runtime.h>

#define NN 20000
#define NE 640000
#define Cc 128
#define C2 256
#define BN_EPS 1e-5f

typedef __attribute__((ext_vector_type(8))) short bf16x8;
typedef __attribute__((ext_vector_type(4))) float f32x4;

// ---- workspace layout (float offsets) ----
#define WS_P     0                      // [NN*Cc]
#define WS_Q     (NN*Cc)                // [NN*Cc]
#define WS_CNTT  (2*NN*Cc)              // [NN] float
#define WS_CNTS  (2*NN*Cc + NN)         // [NN] int
#define WS_STATS (2*NN*Cc + 2*NN)       // [768]: sum1[256], sq1[256], sum2[128], sq2[128]
#define WS_W1PT  (WS_STATS + 768)       // [256*128] transposed folded W1: [c][o]
#define WS_B1P   (WS_W1PT + C2*Cc)      // [128]
#define WS_W2BF  (WS_B1P + Cc)          // ushort[128*128] folded W2 bf16: [o][c]
#define WS_B2P   (WS_W2BF + Cc*Cc)      // [128]

// fp32 -> bf16 round-to-nearest-even
static __device__ inline unsigned short f2bf(float f) {
  union { float f; unsigned u; } v; v.f = f;
  unsigned r = v.u + 0x7fffu + ((v.u >> 16) & 1u);
  return (unsigned short)(r >> 16);
}

__global__ void k_zero(float* __restrict__ stats, int* __restrict__ cntS) {
  int i = blockIdx.x * blockDim.x + threadIdx.x;
  if (i < 768) stats[i] = 0.0f;
  if (i < NN) cntS[i] = 0;
}

__global__ void k_cnt(const int* __restrict__ src, int* __restrict__ cntS) {
  int e = blockIdx.x * blockDim.x + threadIdx.x;
  if (e < NE) atomicAdd(&cntS[src[e]], 1);
}

// one block (128 threads) per node: segment sum of x[src] over the node's
// contiguous (tgt sorted) edge range; 2-way unrolled for gather ILP.
__global__ void k_nbr(const float* __restrict__ x, const int* __restrict__ tgt,
                      const int* __restrict__ src, float* __restrict__ nbr,
                      float* __restrict__ cntT) {
  int node = blockIdx.x;
  int a = 0, b = NE;
  while (a < b) { int m = (a + b) >> 1; if (tgt[m] < node) a = m + 1; else b = m; }
  int lo = a;
  b = NE;
  while (a < b) { int m = (a + b) >> 1; if (tgt[m] <= node) a = m + 1; else b = m; }
  int hi = a;
  int c = threadIdx.x;
  float acc0 = 0.0f, acc1 = 0.0f;
  int e = lo;
  for (; e + 1 < hi; e += 2) {
    acc0 += x[src[e] * Cc + c];
    acc1 += x[src[e + 1] * Cc + c];
  }
  if (e < hi) acc0 += x[src[e] * Cc + c];
  nbr[node * Cc + c] = acc0 + acc1;
  if (c == 0) cntT[node] = (float)(hi - lo);
}

// BN1 stats: count-weighted sums over nodes.
__global__ void k_stats1(const float* __restrict__ nbr, const float* __restrict__ x,
                         const float* __restrict__ cntT, const int* __restrict__ cntS,
                         float* __restrict__ stats) {
  int c = threadIdx.x;
  float sa = 0.f, qa = 0.f, sb = 0.f, qb = 0.f;
  for (int t = blockIdx.x; t < NN; t += gridDim.x) {
    float ct = cntT[t];
    float cs = (float)cntS[t];
    float v1 = nbr[t * Cc + c];
    float v2 = x[t * Cc + c];
    sa += ct * v1; qa += ct * v1 * v1;
    sb += cs * v2; qb += cs * v2 * v2;
  }
  atomicAdd(&stats[c], sa);
  atomicAdd(&stats[256 + c], qa);
  atomicAdd(&stats[128 + c], sb);
  atomicAdd(&stats[256 + 128 + c], qb);
}

// fold BN1 into W1: W1pT[c][o] = W1[o][c]*a1[c];  b1p[o] = b1[o] + sum_c W1[o][c]*c1[c]
__global__ void k_fold1(const float* __restrict__ W1, const float* __restrict__ b1,
                        const float* __restrict__ g1, const float* __restrict__ be1,
                        const float* __restrict__ stats,
                        float* __restrict__ W1pT, float* __restrict__ b1p) {
  __shared__ float red[C2];
  int o = blockIdx.x, c = threadIdx.x;
  const float inv = 1.0f / (float)NE;
  float mu = stats[c] * inv;
  float var = stats[256 + c] * inv - mu * mu;
  float a = g1[c] * rsqrtf(var + BN_EPS);
  float cc = be1[c] - mu * a;
  float w = W1[o * C2 + c];
  W1pT[c * Cc + o] = w * a;
  red[c] = w * cc;
  __syncthreads();
  for (int s = 128; s > 0; s >>= 1) { if (c < s) red[c] += red[c + s]; __syncthreads(); }
  if (c == 0) b1p[o] = b1[o] + red[0];
}

// P = nbr_sum @ W1a'.T ; Q = x @ W1b'.T   (blockIdx.y selects half)
__global__ __launch_bounds__(256) void k_pq(const float* __restrict__ nbr,
                                            const float* __restrict__ x,
                                            const float* __restrict__ W1pT,
                                            float* __restrict__ P,
                                            float* __restrict__ Q) {
  __shared__ float Ar[32][128];
  const int half = blockIdx.y;
  const float* __restrict__ A = half ? x : nbr;
  float* __restrict__ Out = half ? Q : P;
  const float* __restrict__ Wt = W1pT + (half ? Cc * Cc : 0);  // [128 c][128 o]
  int tid = threadIdx.x;
  int r0 = blockIdx.x * 32;
  for (int i = tid; i < 32 * 128; i += 256) {
    int r = i >> 7, c = i & 127;
    Ar[r][c] = A[(r0 + r) * Cc + c];
  }
  __syncthreads();
  int tx = tid & 31, ty = tid >> 5;
  float acc[4][4] = {};
  #pragma unroll 4
  for (int c = 0; c < 128; ++c) {
    float4 w = *(const float4*)&Wt[c * Cc + tx * 4];
    float a0 = Ar[ty * 4 + 0][c], a1 = Ar[ty * 4 + 1][c];
    float a2 = Ar[ty * 4 + 2][c], a3 = Ar[ty * 4 + 3][c];
    acc[0][0] += a0 * w.x; acc[0][1] += a0 * w.y; acc[0][2] += a0 * w.z; acc[0][3] += a0 * w.w;
    acc[1][0] += a1 * w.x; acc[1][1] += a1 * w.y; acc[1][2] += a1 * w.z; acc[1][3] += a1 * w.w;
    acc[2][0] += a2 * w.x; acc[2][1] += a2 * w.y; acc[2][2] += a2 * w.z; acc[2][3] += a2 * w.w;
    acc[3][0] += a3 * w.x; acc[3][1] += a3 * w.y; acc[3][2] += a3 * w.z; acc[3][3] += a3 * w.w;
  }
  #pragma unroll
  for (int i = 0; i < 4; ++i) {
    int node = r0 + ty * 4 + i;
    float4 v = make_float4(acc[i][0], acc[i][1], acc[i][2], acc[i][3]);
    *(float4*)&Out[node * Cc + tx * 4] = v;
  }
}

// BN2 stats: one pass over edges, z recomputed from P,Q.
// 256 threads = 2 edge-lanes x 128 channels; 2500 blocks x 256 edges.
__global__ __launch_bounds__(256) void k_stats2(const float* __restrict__ P,
                                                const float* __restrict__ Q,
                                                const float* __restrict__ b1p,
                                                const int* __restrict__ tgt,
                                                const int* __restrict__ src,
                                                float* __restrict__ stats) {
  __shared__ float s2[Cc], q2[Cc];
  int c = threadIdx.x & 127;
  int y = threadIdx.x >> 7;
  int e0 = blockIdx.x * 256;
  float b = b1p[c];
  float s = 0.f, q = 0.f;
  for (int e = e0 + y; e < e0 + 256; e += 2) {
    int t = tgt[e], sc = src[e];
    float z = fmaxf(P[t * Cc + c] + Q[sc * Cc + c] + b, 0.f);
    s += z; q += z * z;
  }
  if (y) { s2[c] = s; q2[c] = q; }
  __syncthreads();
  if (!y) {
    atomicAdd(&stats[512 + c], s + s2[c]);
    atomicAdd(&stats[640 + c], q + q2[c]);
  }
}

// fold BN2 into W2, emit bf16 [o][c] weights + fp32 bias
__global__ void k_fold2(const float* __restrict__ W2, const float* __restrict__ b2,
                        const float* __restrict__ g2, const float* __restrict__ be2,
                        const float* __restrict__ stats,
                        unsigned short* __restrict__ W2bf, float* __restrict__ b2p) {
  __shared__ float red[Cc];
  int o = blockIdx.x, c = threadIdx.x;
  const float inv = 1.0f / (float)NE;
  float mu = stats[512 + c] * inv;
  float var = stats[640 + c] * inv - mu * mu;
  float a = g2[c] * rsqrtf(var + BN_EPS);
  float cc = be2[c] - mu * a;
  float w = W2[o * Cc + c];
  W2bf[o * Cc + c] = f2bf(w * a);
  red[c] = w * cc;
  __syncthreads();
  for (int s = 64; s > 0; s >>= 1) { if (c < s) red[c] += red[c + s]; __syncthreads(); }
  if (c == 0) b2p[o] = b2[o] + red[0];
}

// out[e][o] = relu( sum_c z[e][c]*W2'[o][c] + b2'[o] ), bf16 MFMA.
// Operand-SWAPPED: D[row=out][col=edge] so each lane holds 4 contiguous outs
// per 16-out tile -> float4 C-stores. 64 edges x 128 outs per block, 4 waves.
#define ZPAD 136
__global__ __launch_bounds__(256) void k_out_mfma(const float* __restrict__ P,
                                                  const float* __restrict__ Q,
                                                  const float* __restrict__ b1p,
                                                  const unsigned short* __restrict__ W2bf,
                                                  const float* __restrict__ b2p,
                                                  const int* __restrict__ tgt,
                                                  const int* __restrict__ src,
                                                  float* __restrict__ out) {
  __shared__ unsigned short Zl[64 * ZPAD];   // 17408 B
  __shared__ unsigned short Wl[128 * ZPAD];  // 34816 B
  int tid = threadIdx.x;
  int e0 = blockIdx.x * 64;

  // stage folded-bf16 W2 [o][c] -> LDS (coalesced 16B loads)
  for (int i = tid; i < 2048; i += 256) {
    int row = i >> 4, col = (i & 15) * 8;
    *(bf16x8*)&Wl[row * ZPAD + col] = *(const bf16x8*)&W2bf[row * Cc + col];
  }
  // stage Z = relu(P[tgt]+Q[src]+b1') in bf16; 4 threads per edge-row
  {
    int r = tid >> 2;
    int c0 = (tid & 3) * 32;
    int e = e0 + r;
    const float* Pr = P + (size_t)tgt[e] * Cc;
    const float* Qr = Q + (size_t)src[e] * Cc;
    #pragma unroll
    for (int j = 0; j < 4; ++j) {
      int c = c0 + j * 8;
      float4 p0 = *(const float4*)&Pr[c];
      float4 p1 = *(const float4*)&Pr[c + 4];
      float4 q0 = *(const float4*)&Qr[c];
      float4 q1 = *(const float4*)&Qr[c + 4];
      float4 b0 = *(const float4*)&b1p[c];
      float4 b1 = *(const float4*)&b1p[c + 4];
      bf16x8 z;
      z[0] = (short)f2bf(fmaxf(p0.x + q0.x + b0.x, 0.f));
      z[1] = (short)f2bf(fmaxf(p0.y + q0.y + b0.y, 0.f));
      z[2] = (short)f2bf(fmaxf(p0.z + q0.z + b0.z, 0.f));
      z[3] = (short)f2bf(fmaxf(p0.w + q0.w + b0.w, 0.f));
      z[4] = (short)f2bf(fmaxf(p1.x + q1.x + b1.x, 0.f));
      z[5] = (short)f2bf(fmaxf(p1.y + q1.y + b1.y, 0.f));
      z[6] = (short)f2bf(fmaxf(p1.z + q1.z + b1.z, 0.f));
      z[7] = (short)f2bf(fmaxf(p1.w + q1.w + b1.w, 0.f));
      *(bf16x8*)&Zl[r * ZPAD + c] = z;
    }
  }
  __syncthreads();

  int w = tid >> 6, l = tid & 63;
  int la = l & 15, kb = l >> 4;           // A-row/B-col = la; k-chunk = kb*8
  f32x4 acc[8];
  #pragma unroll
  for (int n = 0; n < 8; ++n) acc[n] = (f32x4){0.f, 0.f, 0.f, 0.f};

  #pragma unroll
  for (int kk = 0; kk < 4; ++kk) {        // K = 128 in 4 steps of 32
    bf16x8 zb = *(const bf16x8*)&Zl[(w * 16 + la) * ZPAD + kk * 32 + kb * 8];
    #pragma unroll
    for (int n = 0; n < 8; ++n) {         // 8 out-tiles of 16
      bf16x8 wa = *(const bf16x8*)&Wl[(n * 16 + la) * ZPAD + kk * 32 + kb * 8];
      // swapped: A = W' (rows = outs), B = Z (cols = edges)
      acc[n] = __builtin_amdgcn_mfma_f32_16x16x32_bf16(wa, zb, acc[n], 0, 0, 0);
    }
  }

  // D layout: col(edge) = la, row(out) = kb*4 + r  -> contiguous float4 per lane
  int e = e0 + w * 16 + la;
  #pragma unroll
  for (int n = 0; n < 8; ++n) {
    int o0 = n * 16 + kb * 4;
    float4 bb = *(const float4*)&b2p[o0];
    float4 v;
    v.x = fmaxf(acc[n][0] + bb.x, 0.f);
    v.y = fmaxf(acc[n][1] + bb.y, 0.f);
    v.z = fmaxf(acc[n][2] + bb.z, 0.f);
    v.w = fmaxf(acc[n][3] + bb.w, 0.f);
    *(float4*)&out[(size_t)e * Cc + o0] = v;
  }
}

extern "C" void kernel_launch(void* const* d_in, const int* in_sizes, int n_in,
                              void* d_out, int out_size, void* d_ws, size_t ws_size,
                              hipStream_t stream) {
  (void)in_sizes; (void)n_in; (void)out_size; (void)ws_size;
  const float* x   = (const float*)d_in[0];
  const float* g1  = (const float*)d_in[1];
  const float* be1 = (const float*)d_in[2];
  const float* W1  = (const float*)d_in[3];
  const float* b1  = (const float*)d_in[4];
  const float* g2  = (const float*)d_in[5];
  const float* be2 = (const float*)d_in[6];
  const float* W2  = (const float*)d_in[7];
  const float* b2  = (const float*)d_in[8];
  const int* tgt   = (const int*)d_in[9];
  const int* src   = (const int*)d_in[10];

  float* ws  = (float*)d_ws;
  float* out = (float*)d_out;

  float* P     = ws + WS_P;
  float* Q     = ws + WS_Q;
  float* cntT  = ws + WS_CNTT;
  int*   cntS  = (int*)(ws + WS_CNTS);
  float* stats = ws + WS_STATS;
  float* W1pT  = ws + WS_W1PT;
  float* b1p   = ws + WS_B1P;
  unsigned short* W2bf = (unsigned short*)(ws + WS_W2BF);
  float* b2p   = ws + WS_B2P;
  float* nbr   = out;  // scratch: overwritten by k_out_mfma at the end

  k_zero  <<<dim3((NN + 255) / 256), dim3(256), 0, stream>>>(stats, cntS);
  k_cnt   <<<dim3(NE / 256),        dim3(256), 0, stream>>>(src, cntS);
  k_nbr   <<<dim3(NN),              dim3(Cc),  0, stream>>>(x, tgt, src, nbr, cntT);
  k_stats1<<<dim3(256),             dim3(Cc),  0, stream>>>(nbr, x, cntT, cntS, stats);
  k_fold1 <<<dim3(Cc),              dim3(C2),  0, stream>>>(W1, b1, g1, be1, stats, W1pT, b1p);
  k_pq    <<<dim3(NN / 32, 2),      dim3(256), 0, stream>>>(nbr, x, W1pT, P, Q);
  k_stats2<<<dim3(NE / 256),        dim3(256), 0, stream>>>(P, Q, b1p, tgt, src, stats);
  k_fold2 <<<dim3(Cc),              dim3(Cc),  0, stream>>>(W2, b2, g2, be2, stats, W2bf, b2p);
  k_out_mfma<<<dim3(NE / 64),       dim3(256), 0, stream>>>(P, Q, b1p, W2bf, b2p, tgt, src, out);
}

// Round 10
// 408.608 us; speedup vs baseline: 1.2880x; 1.2880x over previous
//
#include <hip/hip_runtime.h>

#define NN 20000
#define NE 640000
#define Cc 128
#define C2 256
#define BN_EPS 1e-5f

typedef __attribute__((ext_vector_type(8))) short bf16x8;
typedef __attribute__((ext_vector_type(4))) float f32x4;

// ---- workspace layout (float offsets) ----
#define WS_P     0                      // [NN*Cc]
#define WS_Q     (NN*Cc)                // [NN*Cc]
#define WS_CNTT  (2*NN*Cc)              // [NN] float
#define WS_CNTS  (2*NN*Cc + NN)         // [NN] int
#define WS_STATS (2*NN*Cc + 2*NN)       // [768]: sum1[256], sq1[256], sum2[128], sq2[128]
#define WS_W1PT  (WS_STATS + 768)       // [256*128] transposed folded W1: [c][o]
#define WS_B1P   (WS_W1PT + C2*Cc)      // [128]
#define WS_W2BF  (WS_B1P + Cc)          // ushort[128*128] folded W2 bf16: [o][c]
#define WS_B2P   (WS_W2BF + Cc*Cc)      // [128]

// fp32 -> bf16 round-to-nearest-even
static __device__ inline unsigned short f2bf(float f) {
  union { float f; unsigned u; } v; v.f = f;
  unsigned r = v.u + 0x7fffu + ((v.u >> 16) & 1u);
  return (unsigned short)(r >> 16);
}

__global__ void k_zero(float* __restrict__ stats, int* __restrict__ cntS) {
  int i = blockIdx.x * blockDim.x + threadIdx.x;
  if (i < 768) stats[i] = 0.0f;
  if (i < NN) cntS[i] = 0;
}

__global__ void k_cnt(const int* __restrict__ src, int* __restrict__ cntS) {
  int e = blockIdx.x * blockDim.x + threadIdx.x;
  if (e < NE) atomicAdd(&cntS[src[e]], 1);
}

// one block (128 threads) per node: segment sum of x[src] over the node's
// contiguous (tgt sorted) edge range, found by binary search.
__global__ void k_nbr(const float* __restrict__ x, const int* __restrict__ tgt,
                      const int* __restrict__ src, float* __restrict__ nbr,
                      float* __restrict__ cntT) {
  int node = blockIdx.x;
  int a = 0, b = NE;
  while (a < b) { int m = (a + b) >> 1; if (tgt[m] < node) a = m + 1; else b = m; }
  int lo = a;
  b = NE;
  while (a < b) { int m = (a + b) >> 1; if (tgt[m] <= node) a = m + 1; else b = m; }
  int hi = a;
  int c = threadIdx.x;
  float acc = 0.0f;
  for (int e = lo; e < hi; ++e) acc += x[src[e] * Cc + c];
  nbr[node * Cc + c] = acc;
  if (c == 0) cntT[node] = (float)(hi - lo);
}

// BN1 stats: count-weighted sums over nodes.
__global__ void k_stats1(const float* __restrict__ nbr, const float* __restrict__ x,
                         const float* __restrict__ cntT, const int* __restrict__ cntS,
                         float* __restrict__ stats) {
  int c = threadIdx.x;
  float sa = 0.f, qa = 0.f, sb = 0.f, qb = 0.f;
  for (int t = blockIdx.x; t < NN; t += gridDim.x) {
    float ct = cntT[t];
    float cs = (float)cntS[t];
    float v1 = nbr[t * Cc + c];
    float v2 = x[t * Cc + c];
    sa += ct * v1; qa += ct * v1 * v1;
    sb += cs * v2; qb += cs * v2 * v2;
  }
  atomicAdd(&stats[c], sa);
  atomicAdd(&stats[256 + c], qa);
  atomicAdd(&stats[128 + c], sb);
  atomicAdd(&stats[256 + 128 + c], qb);
}

// fold BN1 into W1: W1pT[c][o] = W1[o][c]*a1[c];  b1p[o] = b1[o] + sum_c W1[o][c]*c1[c]
__global__ void k_fold1(const float* __restrict__ W1, const float* __restrict__ b1,
                        const float* __restrict__ g1, const float* __restrict__ be1,
                        const float* __restrict__ stats,
                        float* __restrict__ W1pT, float* __restrict__ b1p) {
  __shared__ float red[C2];
  int o = blockIdx.x, c = threadIdx.x;
  const float inv = 1.0f / (float)NE;
  float mu = stats[c] * inv;
  float var = stats[256 + c] * inv - mu * mu;
  float a = g1[c] * rsqrtf(var + BN_EPS);
  float cc = be1[c] - mu * a;
  float w = W1[o * C2 + c];
  W1pT[c * Cc + o] = w * a;
  red[c] = w * cc;
  __syncthreads();
  for (int s = 128; s > 0; s >>= 1) { if (c < s) red[c] += red[c + s]; __syncthreads(); }
  if (c == 0) b1p[o] = b1[o] + red[0];
}

// P = nbr_sum @ W1a'.T ; Q = x @ W1b'.T   (blockIdx.y selects half)
__global__ __launch_bounds__(256) void k_pq(const float* __restrict__ nbr,
                                            const float* __restrict__ x,
                                            const float* __restrict__ W1pT,
                                            float* __restrict__ P,
                                            float* __restrict__ Q) {
  __shared__ float Ar[32][128];
  const int half = blockIdx.y;
  const float* __restrict__ A = half ? x : nbr;
  float* __restrict__ Out = half ? Q : P;
  const float* __restrict__ Wt = W1pT + (half ? Cc * Cc : 0);  // [128 c][128 o]
  int tid = threadIdx.x;
  int r0 = blockIdx.x * 32;
  for (int i = tid; i < 32 * 128; i += 256) {
    int r = i >> 7, c = i & 127;
    Ar[r][c] = A[(r0 + r) * Cc + c];
  }
  __syncthreads();
  int tx = tid & 31, ty = tid >> 5;
  float acc[4][4] = {};
  #pragma unroll 4
  for (int c = 0; c < 128; ++c) {
    float4 w = *(const float4*)&Wt[c * Cc + tx * 4];
    float a0 = Ar[ty * 4 + 0][c], a1 = Ar[ty * 4 + 1][c];
    float a2 = Ar[ty * 4 + 2][c], a3 = Ar[ty * 4 + 3][c];
    acc[0][0] += a0 * w.x; acc[0][1] += a0 * w.y; acc[0][2] += a0 * w.z; acc[0][3] += a0 * w.w;
    acc[1][0] += a1 * w.x; acc[1][1] += a1 * w.y; acc[1][2] += a1 * w.z; acc[1][3] += a1 * w.w;
    acc[2][0] += a2 * w.x; acc[2][1] += a2 * w.y; acc[2][2] += a2 * w.z; acc[2][3] += a2 * w.w;
    acc[3][0] += a3 * w.x; acc[3][1] += a3 * w.y; acc[3][2] += a3 * w.z; acc[3][3] += a3 * w.w;
  }
  #pragma unroll
  for (int i = 0; i < 4; ++i) {
    int node = r0 + ty * 4 + i;
    float4 v = make_float4(acc[i][0], acc[i][1], acc[i][2], acc[i][3]);
    *(float4*)&Out[node * Cc + tx * 4] = v;
  }
}

// BN2 stats: one pass over edges, z recomputed from P,Q (round-8 form).
__global__ void k_stats2(const float* __restrict__ P, const float* __restrict__ Q,
                         const float* __restrict__ b1p,
                         const int* __restrict__ tgt, const int* __restrict__ src,
                         float* __restrict__ stats) {
  int c = threadIdx.x;
  int e0 = blockIdx.x * 512;
  float b = b1p[c];
  float s = 0.f, q = 0.f;
  for (int e = e0; e < e0 + 512; ++e) {
    int t = tgt[e], sc = src[e];
    float z = P[t * Cc + c] + Q[sc * Cc + c] + b;
    z = fmaxf(z, 0.f);
    s += z; q += z * z;
  }
  atomicAdd(&stats[512 + c], s);
  atomicAdd(&stats[640 + c], q);
}

// fold BN2 into W2, emit bf16 [o][c] weights + fp32 bias
__global__ void k_fold2(const float* __restrict__ W2, const float* __restrict__ b2,
                        const float* __restrict__ g2, const float* __restrict__ be2,
                        const float* __restrict__ stats,
                        unsigned short* __restrict__ W2bf, float* __restrict__ b2p) {
  __shared__ float red[Cc];
  int o = blockIdx.x, c = threadIdx.x;
  const float inv = 1.0f / (float)NE;
  float mu = stats[512 + c] * inv;
  float var = stats[640 + c] * inv - mu * mu;
  float a = g2[c] * rsqrtf(var + BN_EPS);
  float cc = be2[c] - mu * a;
  float w = W2[o * Cc + c];
  W2bf[o * Cc + c] = f2bf(w * a);
  red[c] = w * cc;
  __syncthreads();
  for (int s = 64; s > 0; s >>= 1) { if (c < s) red[c] += red[c + s]; __syncthreads(); }
  if (c == 0) b2p[o] = b2[o] + red[0];
}

// out[e][o] = relu( z[e]@W2' + b2' ), bf16 MFMA, Z gathered DIRECTLY into
// A-fragments (no Z LDS, one barrier). 64 edges x 128 outs per block, 4 waves.
// Lane l: la=l&15 -> edge row; kb=l>>4 -> k-chunk. A-frag k = kk*32+kb*8+j.
// LDS = W only: [128][WPAD=136] bf16 -> ~2-way bank aliasing (free, m136).
#define WPAD 136
__global__ __launch_bounds__(256) void k_out_mfma(const float* __restrict__ P,
                                                  const float* __restrict__ Q,
                                                  const float* __restrict__ b1p,
                                                  const unsigned short* __restrict__ W2bf,
                                                  const float* __restrict__ b2p,
                                                  const int* __restrict__ tgt,
                                                  const int* __restrict__ src,
                                                  float* __restrict__ out) {
  __shared__ unsigned short Wl[128 * WPAD];  // 34816 B -> 4 blocks/CU
  int tid = threadIdx.x;
  int e0 = blockIdx.x * 64;

  // stage folded-bf16 W2 [o][c] -> LDS (coalesced 16B loads)
  for (int i = tid; i < 2048; i += 256) {
    int row = i >> 4, col = (i & 15) * 8;
    *(bf16x8*)&Wl[row * WPAD + col] = *(const bf16x8*)&W2bf[row * Cc + col];
  }

  int w = tid >> 6, l = tid & 63;
  int la = l & 15, kb = l >> 4;
  int e = e0 + w * 16 + la;
  const float* __restrict__ Pr = P + (size_t)tgt[e] * Cc;
  const float* __restrict__ Qr = Q + (size_t)src[e] * Cc;
  __syncthreads();

  f32x4 acc[8];
  #pragma unroll
  for (int n = 0; n < 8; ++n) acc[n] = (f32x4){0.f, 0.f, 0.f, 0.f};

  #pragma unroll
  for (int kk = 0; kk < 4; ++kk) {        // K = 128 in 4 steps of 32
    int c = kk * 32 + kb * 8;
    float4 p0 = *(const float4*)&Pr[c];
    float4 p1 = *(const float4*)&Pr[c + 4];
    float4 q0 = *(const float4*)&Qr[c];
    float4 q1 = *(const float4*)&Qr[c + 4];
    float4 b0 = *(const float4*)&b1p[c];
    float4 b1v = *(const float4*)&b1p[c + 4];
    bf16x8 a;
    a[0] = (short)f2bf(fmaxf(p0.x + q0.x + b0.x, 0.f));
    a[1] = (short)f2bf(fmaxf(p0.y + q0.y + b0.y, 0.f));
    a[2] = (short)f2bf(fmaxf(p0.z + q0.z + b0.z, 0.f));
    a[3] = (short)f2bf(fmaxf(p0.w + q0.w + b0.w, 0.f));
    a[4] = (short)f2bf(fmaxf(p1.x + q1.x + b1v.x, 0.f));
    a[5] = (short)f2bf(fmaxf(p1.y + q1.y + b1v.y, 0.f));
    a[6] = (short)f2bf(fmaxf(p1.z + q1.z + b1v.z, 0.f));
    a[7] = (short)f2bf(fmaxf(p1.w + q1.w + b1v.w, 0.f));
    #pragma unroll
    for (int n = 0; n < 8; ++n) {         // 8 out-tiles of 16
      bf16x8 b = *(const bf16x8*)&Wl[(n * 16 + la) * WPAD + c];
      acc[n] = __builtin_amdgcn_mfma_f32_16x16x32_bf16(a, b, acc[n], 0, 0, 0);
    }
  }

  // C/D layout: col(out) = la, row(edge) = kb*4 + r  (round-8 verified epilogue)
  int r0 = kb * 4;
  #pragma unroll
  for (int n = 0; n < 8; ++n) {
    int col = n * 16 + la;
    float bb = b2p[col];
    #pragma unroll
    for (int r = 0; r < 4; ++r) {
      int eo = e0 + w * 16 + r0 + r;
      out[(size_t)eo * Cc + col] = fmaxf(acc[n][r] + bb, 0.f);
    }
  }
}

extern "C" void kernel_launch(void* const* d_in, const int* in_sizes, int n_in,
                              void* d_out, int out_size, void* d_ws, size_t ws_size,
                              hipStream_t stream) {
  (void)in_sizes; (void)n_in; (void)out_size; (void)ws_size;
  const float* x   = (const float*)d_in[0];
  const float* g1  = (const float*)d_in[1];
  const float* be1 = (const float*)d_in[2];
  const float* W1  = (const float*)d_in[3];
  const float* b1  = (const float*)d_in[4];
  const float* g2  = (const float*)d_in[5];
  const float* be2 = (const float*)d_in[6];
  const float* W2  = (const float*)d_in[7];
  const float* b2  = (const float*)d_in[8];
  const int* tgt   = (const int*)d_in[9];
  const int* src   = (const int*)d_in[10];

  float* ws  = (float*)d_ws;
  float* out = (float*)d_out;

  float* P     = ws + WS_P;
  float* Q     = ws + WS_Q;
  float* cntT  = ws + WS_CNTT;
  int*   cntS  = (int*)(ws + WS_CNTS);
  float* stats = ws + WS_STATS;
  float* W1pT  = ws + WS_W1PT;
  float* b1p   = ws + WS_B1P;
  unsigned short* W2bf = (unsigned short*)(ws + WS_W2BF);
  float* b2p   = ws + WS_B2P;
  float* nbr   = out;  // scratch: overwritten by k_out_mfma at the end

  k_zero  <<<dim3((NN + 255) / 256), dim3(256), 0, stream>>>(stats, cntS);
  k_cnt   <<<dim3(NE / 256),        dim3(256), 0, stream>>>(src, cntS);
  k_nbr   <<<dim3(NN),              dim3(Cc),  0, stream>>>(x, tgt, src, nbr, cntT);
  k_stats1<<<dim3(256),             dim3(Cc),  0, stream>>>(nbr, x, cntT, cntS, stats);
  k_fold1 <<<dim3(Cc),              dim3(C2),  0, stream>>>(W1, b1, g1, be1, stats, W1pT, b1p);
  k_pq    <<<dim3(NN / 32, 2),      dim3(256), 0, stream>>>(nbr, x, W1pT, P, Q);
  k_stats2<<<dim3(NE / 512),        dim3(Cc),  0, stream>>>(P, Q, b1p, tgt, src, stats);
  k_fold2 <<<dim3(Cc),              dim3(Cc),  0, stream>>>(W2, b2, g2, be2, stats, W2bf, b2p);
  k_out_mfma<<<dim3(NE / 64),       dim3(256), 0, stream>>>(P, Q, b1p, W2bf, b2p, tgt, src, out);
}

// Round 11
// 393.730 us; speedup vs baseline: 1.3367x; 1.0378x over previous
//
#include <hip/hip_runtime.h>

#define NN 20000
#define NE 640000
#define Cc 128
#define C2 256
#define BN_EPS 1e-5f

typedef __attribute__((ext_vector_type(8))) short bf16x8;
typedef __attribute__((ext_vector_type(4))) float f32x4;

// ---- workspace layout (float offsets) ----
#define WS_P     0                      // [NN*Cc]
#define WS_Q     (NN*Cc)                // [NN*Cc]
#define WS_CNTT  (2*NN*Cc)              // [NN] float
#define WS_CNTS  (2*NN*Cc + NN)         // [NN] int
#define WS_STATS (2*NN*Cc + 2*NN)       // [768]: sum1[256], sq1[256], sum2[128], sq2[128]
#define WS_W1PT  (WS_STATS + 768)       // [256*128] transposed folded W1: [c][o]
#define WS_B1P   (WS_W1PT + C2*Cc)      // [128]
#define WS_W2BF  (WS_B1P + Cc)          // ushort[128*128] folded W2 bf16: [o][c]
#define WS_B2P   (WS_W2BF + Cc*Cc)      // [128]

// z (bf16) for edge e lives in the FIRST 256 B of out-row e's 512 B slot:
// ushort index e*256 + c. Written by k_stats2, read (then overwritten) by
// k_out_mfma's own wave -> no race (reads complete into regs before stores).

// fp32 -> bf16 round-to-nearest-even
static __device__ inline unsigned short f2bf(float f) {
  union { float f; unsigned u; } v; v.f = f;
  unsigned r = v.u + 0x7fffu + ((v.u >> 16) & 1u);
  return (unsigned short)(r >> 16);
}

__global__ void k_zero(float* __restrict__ stats, int* __restrict__ cntS) {
  int i = blockIdx.x * blockDim.x + threadIdx.x;
  if (i < 768) stats[i] = 0.0f;
  if (i < NN) cntS[i] = 0;
}

__global__ void k_cnt(const int* __restrict__ src, int* __restrict__ cntS) {
  int e = blockIdx.x * blockDim.x + threadIdx.x;
  if (e < NE) atomicAdd(&cntS[src[e]], 1);
}

// one block (128 threads) per node: segment sum of x[src] over the node's
// contiguous (tgt sorted) edge range, found by binary search.
__global__ void k_nbr(const float* __restrict__ x, const int* __restrict__ tgt,
                      const int* __restrict__ src, float* __restrict__ nbr,
                      float* __restrict__ cntT) {
  int node = blockIdx.x;
  int a = 0, b = NE;
  while (a < b) { int m = (a + b) >> 1; if (tgt[m] < node) a = m + 1; else b = m; }
  int lo = a;
  b = NE;
  while (a < b) { int m = (a + b) >> 1; if (tgt[m] <= node) a = m + 1; else b = m; }
  int hi = a;
  int c = threadIdx.x;
  float acc = 0.0f;
  for (int e = lo; e < hi; ++e) acc += x[src[e] * Cc + c];
  nbr[node * Cc + c] = acc;
  if (c == 0) cntT[node] = (float)(hi - lo);
}

// BN1 stats: count-weighted sums over nodes.
__global__ void k_stats1(const float* __restrict__ nbr, const float* __restrict__ x,
                         const float* __restrict__ cntT, const int* __restrict__ cntS,
                         float* __restrict__ stats) {
  int c = threadIdx.x;
  float sa = 0.f, qa = 0.f, sb = 0.f, qb = 0.f;
  for (int t = blockIdx.x; t < NN; t += gridDim.x) {
    float ct = cntT[t];
    float cs = (float)cntS[t];
    float v1 = nbr[t * Cc + c];
    float v2 = x[t * Cc + c];
    sa += ct * v1; qa += ct * v1 * v1;
    sb += cs * v2; qb += cs * v2 * v2;
  }
  atomicAdd(&stats[c], sa);
  atomicAdd(&stats[256 + c], qa);
  atomicAdd(&stats[128 + c], sb);
  atomicAdd(&stats[256 + 128 + c], qb);
}

// fold BN1 into W1: W1pT[c][o] = W1[o][c]*a1[c];  b1p[o] = b1[o] + sum_c W1[o][c]*c1[c]
__global__ void k_fold1(const float* __restrict__ W1, const float* __restrict__ b1,
                        const float* __restrict__ g1, const float* __restrict__ be1,
                        const float* __restrict__ stats,
                        float* __restrict__ W1pT, float* __restrict__ b1p) {
  __shared__ float red[C2];
  int o = blockIdx.x, c = threadIdx.x;
  const float inv = 1.0f / (float)NE;
  float mu = stats[c] * inv;
  float var = stats[256 + c] * inv - mu * mu;
  float a = g1[c] * rsqrtf(var + BN_EPS);
  float cc = be1[c] - mu * a;
  float w = W1[o * C2 + c];
  W1pT[c * Cc + o] = w * a;
  red[c] = w * cc;
  __syncthreads();
  for (int s = 128; s > 0; s >>= 1) { if (c < s) red[c] += red[c + s]; __syncthreads(); }
  if (c == 0) b1p[o] = b1[o] + red[0];
}

// P = nbr_sum @ W1a'.T ; Q = x @ W1b'.T   (blockIdx.y selects half)
__global__ __launch_bounds__(256) void k_pq(const float* __restrict__ nbr,
                                            const float* __restrict__ x,
                                            const float* __restrict__ W1pT,
                                            float* __restrict__ P,
                                            float* __restrict__ Q) {
  __shared__ float Ar[32][128];
  const int half = blockIdx.y;
  const float* __restrict__ A = half ? x : nbr;
  float* __restrict__ Out = half ? Q : P;
  const float* __restrict__ Wt = W1pT + (half ? Cc * Cc : 0);  // [128 c][128 o]
  int tid = threadIdx.x;
  int r0 = blockIdx.x * 32;
  for (int i = tid; i < 32 * 128; i += 256) {
    int r = i >> 7, c = i & 127;
    Ar[r][c] = A[(r0 + r) * Cc + c];
  }
  __syncthreads();
  int tx = tid & 31, ty = tid >> 5;
  float acc[4][4] = {};
  #pragma unroll 4
  for (int c = 0; c < 128; ++c) {
    float4 w = *(const float4*)&Wt[c * Cc + tx * 4];
    float a0 = Ar[ty * 4 + 0][c], a1 = Ar[ty * 4 + 1][c];
    float a2 = Ar[ty * 4 + 2][c], a3 = Ar[ty * 4 + 3][c];
    acc[0][0] += a0 * w.x; acc[0][1] += a0 * w.y; acc[0][2] += a0 * w.z; acc[0][3] += a0 * w.w;
    acc[1][0] += a1 * w.x; acc[1][1] += a1 * w.y; acc[1][2] += a1 * w.z; acc[1][3] += a1 * w.w;
    acc[2][0] += a2 * w.x; acc[2][1] += a2 * w.y; acc[2][2] += a2 * w.z; acc[2][3] += a2 * w.w;
    acc[3][0] += a3 * w.x; acc[3][1] += a3 * w.y; acc[3][2] += a3 * w.z; acc[3][3] += a3 * w.w;
  }
  #pragma unroll
  for (int i = 0; i < 4; ++i) {
    int node = r0 + ty * 4 + i;
    float4 v = make_float4(acc[i][0], acc[i][1], acc[i][2], acc[i][3]);
    *(float4*)&Out[node * Cc + tx * 4] = v;
  }
}

// BN2 stats + z materialization: one pass over edges; z (bf16, the exact MFMA
// input) is stashed in the first 256 B of each out-row's 512 B slot.
__global__ void k_stats2(const float* __restrict__ P, const float* __restrict__ Q,
                         const float* __restrict__ b1p,
                         const int* __restrict__ tgt, const int* __restrict__ src,
                         float* __restrict__ stats, unsigned short* __restrict__ zout) {
  int c = threadIdx.x;
  int e0 = blockIdx.x * 512;
  float b = b1p[c];
  float s = 0.f, q = 0.f;
  for (int e = e0; e < e0 + 512; ++e) {
    int t = tgt[e], sc = src[e];
    float z = P[t * Cc + c] + Q[sc * Cc + c] + b;
    z = fmaxf(z, 0.f);
    zout[(size_t)e * 256 + c] = f2bf(z);
    s += z; q += z * z;
  }
  atomicAdd(&stats[512 + c], s);
  atomicAdd(&stats[640 + c], q);
}

// fold BN2 into W2, emit bf16 [o][c] weights + fp32 bias
__global__ void k_fold2(const float* __restrict__ W2, const float* __restrict__ b2,
                        const float* __restrict__ g2, const float* __restrict__ be2,
                        const float* __restrict__ stats,
                        unsigned short* __restrict__ W2bf, float* __restrict__ b2p) {
  __shared__ float red[Cc];
  int o = blockIdx.x, c = threadIdx.x;
  const float inv = 1.0f / (float)NE;
  float mu = stats[512 + c] * inv;
  float var = stats[640 + c] * inv - mu * mu;
  float a = g2[c] * rsqrtf(var + BN_EPS);
  float cc = be2[c] - mu * a;
  float w = W2[o * Cc + c];
  W2bf[o * Cc + c] = f2bf(w * a);
  red[c] = w * cc;
  __syncthreads();
  for (int s = 64; s > 0; s >>= 1) { if (c < s) red[c] += red[c + s]; __syncthreads(); }
  if (c == 0) b2p[o] = b2[o] + red[0];
}

// out[e][o] = relu( z[e]@W2' + b2' ): pure streaming bf16 MFMA GEMM.
// z read from the first 256 B of each out-row (loaded fully into registers
// before any store -> safe in-place overwrite). 64 edges x 128 outs, 4 waves.
#define WPAD 136
__global__ __launch_bounds__(256) void k_out_mfma(const unsigned short* __restrict__ zin,
                                                  const unsigned short* __restrict__ W2bf,
                                                  const float* __restrict__ b2p,
                                                  float* __restrict__ out) {
  __shared__ unsigned short Wl[128 * WPAD];  // 34816 B -> 4 blocks/CU
  int tid = threadIdx.x;
  int e0 = blockIdx.x * 64;

  // stage folded-bf16 W2 [o][c] -> LDS (coalesced 16B loads)
  for (int i = tid; i < 2048; i += 256) {
    int row = i >> 4, col = (i & 15) * 8;
    *(bf16x8*)&Wl[row * WPAD + col] = *(const bf16x8*)&W2bf[row * Cc + col];
  }

  int w = tid >> 6, l = tid & 63;
  int la = l & 15, kb = l >> 4;
  int e = e0 + w * 16 + la;

  // load all 4 A-fragments (full z row slice) into registers up front
  bf16x8 afr[4];
  #pragma unroll
  for (int kk = 0; kk < 4; ++kk)
    afr[kk] = *(const bf16x8*)&zin[(size_t)e * 256 + kk * 32 + kb * 8];
  __syncthreads();

  f32x4 acc[8];
  #pragma unroll
  for (int n = 0; n < 8; ++n) acc[n] = (f32x4){0.f, 0.f, 0.f, 0.f};

  #pragma unroll
  for (int kk = 0; kk < 4; ++kk) {        // K = 128 in 4 steps of 32
    #pragma unroll
    for (int n = 0; n < 8; ++n) {         // 8 out-tiles of 16
      bf16x8 b = *(const bf16x8*)&Wl[(n * 16 + la) * WPAD + kk * 32 + kb * 8];
      acc[n] = __builtin_amdgcn_mfma_f32_16x16x32_bf16(afr[kk], b, acc[n], 0, 0, 0);
    }
  }

  // C/D layout: col(out) = la, row(edge) = kb*4 + r  (verified epilogue)
  int r0 = kb * 4;
  #pragma unroll
  for (int n = 0; n < 8; ++n) {
    int col = n * 16 + la;
    float bb = b2p[col];
    #pragma unroll
    for (int r = 0; r < 4; ++r) {
      int eo = e0 + w * 16 + r0 + r;
      out[(size_t)eo * Cc + col] = fmaxf(acc[n][r] + bb, 0.f);
    }
  }
}

extern "C" void kernel_launch(void* const* d_in, const int* in_sizes, int n_in,
                              void* d_out, int out_size, void* d_ws, size_t ws_size,
                              hipStream_t stream) {
  (void)in_sizes; (void)n_in; (void)out_size; (void)ws_size;
  const float* x   = (const float*)d_in[0];
  const float* g1  = (const float*)d_in[1];
  const float* be1 = (const float*)d_in[2];
  const float* W1  = (const float*)d_in[3];
  const float* b1  = (const float*)d_in[4];
  const float* g2  = (const float*)d_in[5];
  const float* be2 = (const float*)d_in[6];
  const float* W2  = (const float*)d_in[7];
  const float* b2  = (const float*)d_in[8];
  const int* tgt   = (const int*)d_in[9];
  const int* src   = (const int*)d_in[10];

  float* ws  = (float*)d_ws;
  float* out = (float*)d_out;

  float* P     = ws + WS_P;
  float* Q     = ws + WS_Q;
  float* cntT  = ws + WS_CNTT;
  int*   cntS  = (int*)(ws + WS_CNTS);
  float* stats = ws + WS_STATS;
  float* W1pT  = ws + WS_W1PT;
  float* b1p   = ws + WS_B1P;
  unsigned short* W2bf = (unsigned short*)(ws + WS_W2BF);
  float* b2p   = ws + WS_B2P;
  float* nbr   = out;  // scratch: overwritten by k_stats2's z + k_out_mfma

  k_zero  <<<dim3((NN + 255) / 256), dim3(256), 0, stream>>>(stats, cntS);
  k_cnt   <<<dim3(NE / 256),        dim3(256), 0, stream>>>(src, cntS);
  k_nbr   <<<dim3(NN),              dim3(Cc),  0, stream>>>(x, tgt, src, nbr, cntT);
  k_stats1<<<dim3(256),             dim3(Cc),  0, stream>>>(nbr, x, cntT, cntS, stats);
  k_fold1 <<<dim3(Cc),              dim3(C2),  0, stream>>>(W1, b1, g1, be1, stats, W1pT, b1p);
  k_pq    <<<dim3(NN / 32, 2),      dim3(256), 0, stream>>>(nbr, x, W1pT, P, Q);
  k_stats2<<<dim3(NE / 512),        dim3(Cc),  0, stream>>>(P, Q, b1p, tgt, src, stats,
                                                            (unsigned short*)out);
  k_fold2 <<<dim3(Cc),              dim3(Cc),  0, stream>>>(W2, b2, g2, be2, stats, W2bf, b2p);
  k_out_mfma<<<dim3(NE / 64),       dim3(256), 0, stream>>>((const unsigned short*)out,
                                                            W2bf, b2p, out);
}